// Round 1
// 176.394 us; speedup vs baseline: 1.3331x; 1.3331x over previous
//
#include <hip/hip_runtime.h>
#include <math.h>

#define Himg 128
#define Wimg 128
#define HW   16384      // 128*128
#define Cin  64
#define Kk   9
#define OUTC 128
#define Bsz  8

typedef __attribute__((ext_vector_type(8))) _Float16 half8;
typedef __attribute__((ext_vector_type(4))) float   floatx4;

// ---------------------------------------------------------------------------
// transpose+convert: x[b][c][h][w] f32 -> xt[b][h][w][c] f16
// one block per (b,h) row; LDS tile 64ch x 128w (pad 130 -> 2-way-max banks)
// ---------------------------------------------------------------------------
__global__ __launch_bounds__(256) void transpose_x(const float* __restrict__ x,
                                                   _Float16* __restrict__ xt) {
    __shared__ _Float16 tile[Cin][130];
    int t   = threadIdx.x;
    int bid = blockIdx.x;            // 0..1023
    int b   = bid >> 7;
    int h   = bid & 127;
    const float* xb = x + (size_t)b * Cin * HW + (size_t)h * Wimg;
#pragma unroll
    for (int j = 0; j < 32; ++j) {
        int e = t + j * 256;         // 0..8191
        int c = e >> 7;
        int w = e & 127;
        tile[c][w] = (_Float16)xb[(size_t)c * HW + w];
    }
    __syncthreads();
    unsigned* dst = (unsigned*)xt + ((size_t)b * HW + (size_t)h * Wimg) * 32;
#pragma unroll
    for (int j = 0; j < 16; ++j) {
        int d  = t + j * 256;        // 0..4095
        int w  = d >> 5;
        int cp = d & 31;
        union { unsigned u; _Float16 hh[2]; } pk;
        pk.hh[0] = tile[2 * cp][w];
        pk.hh[1] = tile[2 * cp + 1][w];
        dst[d] = pk.u;
    }
}

// ---------------------------------------------------------------------------
// repack main conv weights in MFMA-fragment order:
// half8 index f = (ch*8 + mt)*64 + lane, lane=(kq,ln16); element i of f maps
// to o = mt*16+ln16, kl = kq*8+i, c = (ch&1)*32+kl, kt = ch>>1.
// A wave's A-fragment load is then ONE 1KB-contiguous region.
// ---------------------------------------------------------------------------
__global__ __launch_bounds__(256) void repack_w(const float* __restrict__ w_conv,
                                                _Float16* __restrict__ wpk_h) {
    int idx = blockIdx.x * 256 + threadIdx.x;            // 0 .. 73727
    if (idx >= Kk * Cin * OUTC) return;
    int i    = idx & 7;
    int l    = (idx >> 3) & 63;
    int g    = idx >> 9;             // 0..143
    int mt   = g & 7;
    int ch   = g >> 3;               // 0..17
    int kq   = l >> 4;
    int ln16 = l & 15;
    int o    = mt * 16 + ln16;
    int kl   = kq * 8 + i;
    int c    = (ch & 1) * 32 + kl;
    int kt   = ch >> 1;
    wpk_h[idx] = (_Float16)w_conv[(o * Cin + c) * 9 + kt];
}

// ---------------------------------------------------------------------------
// repack offset+mask weights in fragment order:
// half8 index f = (ch*2 + mt0)*64 + lane; m = mt0*16+ln16 (0..17 offset,
// 18..26 mask, 27..31 zero), kl = kq*8+i.
// ---------------------------------------------------------------------------
__global__ __launch_bounds__(256) void repack_w2(const float* __restrict__ w_offset,
                                                 const float* __restrict__ w_mask,
                                                 _Float16* __restrict__ wpk2) {
    int idx = blockIdx.x * 256 + threadIdx.x;            // 0 .. 18431
    if (idx >= 18 * 32 * 32) return;
    int i    = idx & 7;
    int l    = (idx >> 3) & 63;
    int g    = idx >> 9;             // 0..35
    int mt0  = g & 1;
    int ch   = g >> 1;               // 0..17
    int kq   = l >> 4;
    int ln16 = l & 15;
    int m    = mt0 * 16 + ln16;
    int kl   = kq * 8 + i;
    int c    = (ch & 1) * 32 + kl;
    int kt   = ch >> 1;
    float v = 0.0f;
    if (m < 18)      v = w_offset[(m * Cin + c) * 9 + kt];
    else if (m < 27) v = w_mask[((m - 18) * Cin + c) * 9 + kt];
    wpk2[idx] = (_Float16)v;
}

// ---------------------------------------------------------------------------
// Fused kernel. Lane mapping for all x-side memory: q = t>>2 (pixel),
// c4 = t&3 (16B channel-quarter) -> 4 consecutive lanes read one contiguous
// 64B half-cell (4x fewer cache-line requests than pixel-per-lane).
// Weights: direct global->VGPR fragment loads (layout-matched, 1KB/wave,
// prefetched one chunk ahead) -- no LDS round trip for A operands.
// LDS: only V tiles + P (18.7 KB vs 30 KB before).
// ---------------------------------------------------------------------------
__global__ __launch_bounds__(256, 3) void deform_fused(
        const _Float16* __restrict__ xt, const _Float16* __restrict__ wpk_h,
        const _Float16* __restrict__ wpk2,
        const float* __restrict__ b_offset, const float* __restrict__ b_mask,
        float* __restrict__ out) {
    __shared__ union SMem {
        struct { _Float16 V0[2][64][40]; float P[32][66]; } p0;  // 18688 B
        struct { _Float16 V[2][64][40]; } p1;                    // 10240 B
    } sm;

    int t    = threadIdx.x;
    int bid  = blockIdx.x;
    int b    = bid & 7;                      // XCD-batch swizzle
    int pb   = bid >> 3;                     // 0..255
    int pix0 = pb * 64;
    int h    = pix0 >> 7;
    int w0   = pix0 & 127;                   // 0 or 64

    int lane = t & 63;
    int wv   = t >> 6;
    int q    = t >> 2;                       // pixel 0..63 (block-wide)
    int c4   = t & 3;                        // channel quarter (16B) in 32-ch half
    int kq   = lane >> 4;
    int ln16 = lane & 15;

    const _Float16* xtb  = xt + (size_t)b * HW * Cin;
    const half8* wsrc    = (const half8*)wpk_h;
    const half8* w2src   = (const half8*)wpk2;

    // ================= phase 0: offset/mask conv =================
    floatx4 acc2[2];
    acc2[0] = (floatx4){0.f, 0.f, 0.f, 0.f};
    acc2[1] = (floatx4){0.f, 0.f, 0.f, 0.f};
    int mt0 = wv & 1;                        // wave's m-tile
    int ntA = wv >> 1;                       // wave's n-tiles: ntA, ntA+2

    half8 pv, af;
    {   // prefetch chunk 0 (kt=0: row=h-1, col=w0+q-1, cg=0)
        int row = h - 1, col = w0 + q - 1;
        bool okc = (row >= 0) && (col >= 0) && (col < Wimg);
        if (okc) pv = *(const half8*)(xtb + ((size_t)(row * Wimg + col)) * Cin + c4 * 8);
        else {
#pragma unroll
            for (int i = 0; i < 8; ++i) pv[i] = (_Float16)0.f;
        }
        af = w2src[(size_t)mt0 * 64 + lane];
    }

#pragma unroll
    for (int ch = 0; ch < 18; ++ch) {
        int buf = ch & 1;
        *(half8*)&sm.p0.V0[buf][q][c4 * 8] = pv;
        half8 afc = af;
        if (ch < 17) {
            int chn = ch + 1, ktn = chn >> 1, cgn = chn & 1;
            int row = h + (ktn / 3) - 1;
            int col = w0 + q + (ktn % 3) - 1;
            bool okc = (row >= 0) && (row < Himg) && (col >= 0) && (col < Wimg);
            if (okc) pv = *(const half8*)(xtb + ((size_t)(row * Wimg + col)) * Cin
                                          + cgn * 32 + c4 * 8);
            else {
#pragma unroll
                for (int i = 0; i < 8; ++i) pv[i] = (_Float16)0.f;
            }
            af = w2src[((size_t)chn * 2 + mt0) * 64 + lane];
        }
        __syncthreads();
        half8 b0 = *(const half8*)&sm.p0.V0[buf][ntA * 16 + ln16][kq * 8];
        half8 b1 = *(const half8*)&sm.p0.V0[buf][(ntA + 2) * 16 + ln16][kq * 8];
        acc2[0] = __builtin_amdgcn_mfma_f32_16x16x32_f16(afc, b0, acc2[0], 0, 0, 0);
        acc2[1] = __builtin_amdgcn_mfma_f32_16x16x32_f16(afc, b1, acc2[1], 0, 0, 0);
    }
    // write P (27 used rows x 64 px, fp32) — P disjoint from V0, no race
#pragma unroll
    for (int j = 0; j < 2; ++j) {
        int nt = ntA + 2 * j;
#pragma unroll
        for (int r = 0; r < 4; ++r)
            sm.p0.P[mt0 * 16 + kq * 4 + r][nt * 16 + ln16] = acc2[j][r];
    }
    __syncthreads();

    // ---- per-pixel geometry (pixel q) -> registers ----
    int      o00r[9], packr[9];
    unsigned wab[9], wcd[9];                 // f16-packed (w00,w01),(w10,w11)
    {
        float fh = (float)h, fw = (float)(w0 + q);
#pragma unroll
        for (int k = 0; k < 9; ++k) {
            float dyv = sm.p0.P[2 * k][q]     + b_offset[2 * k];
            float dxv = sm.p0.P[2 * k + 1][q] + b_offset[2 * k + 1];
            float mz  = sm.p0.P[18 + k][q]    + b_mask[k];
            float mkv = 1.0f / (1.0f + expf(-mz));

            float gy  = fh + (float)(k / 3) - 1.0f + dyv;
            float gx  = fw + (float)(k % 3) - 1.0f + dxv;
            float y0f = floorf(gy), x0f = floorf(gx);
            int   y0  = (int)y0f,   x0 = (int)x0f;
            float wy  = gy - y0f,   wx = gx - x0f;
            int   y1  = y0 + 1,     x1 = x0 + 1;

            bool vy0 = (y0 >= 0) && (y0 < Himg);
            bool vy1 = (y1 >= 0) && (y1 < Himg);
            bool vx0 = (x0 >= 0) && (x0 < Wimg);
            bool vx1 = (x1 >= 0) && (x1 < Wimg);

            float w00 = (vy0 && vx0) ? (1.0f - wy) * (1.0f - wx) * mkv : 0.0f;
            float w01 = (vy0 && vx1) ? (1.0f - wy) * wx          * mkv : 0.0f;
            float w10 = (vy1 && vx0) ? wy          * (1.0f - wx) * mkv : 0.0f;
            float w11 = (vy1 && vx1) ? wy          * wx          * mkv : 0.0f;

            int y0c = min(max(y0, 0), Himg - 1), y1c = min(max(y1, 0), Himg - 1);
            int x0c = min(max(x0, 0), Wimg - 1), x1c = min(max(x1, 0), Wimg - 1);
            o00r[k]  = y0c * Wimg + x0c;                       // CELL index
            packr[k] = (x1c - x0c) | ((y1c - y0c) << 16);
            union { unsigned u; _Float16 hh[2]; } pk;
            pk.hh[0] = (_Float16)w00; pk.hh[1] = (_Float16)w01; wab[k] = pk.u;
            pk.hh[0] = (_Float16)w10; pk.hh[1] = (_Float16)w11; wcd[k] = pk.u;
        }
    }

    // ================= phase 1: deformable sampling + GEMM =================
    floatx4 acc[2][4];
#pragma unroll
    for (int i = 0; i < 2; ++i)
#pragma unroll
        for (int j = 0; j < 4; ++j) acc[i][j] = (floatx4){0.f, 0.f, 0.f, 0.f};
    int m0 = wv * 32;

    half8 ga, gb, gc, gd, ar0, ar1;
    {   // prefetch chunk 0 (register-only; before the union-transition sync)
        int o00 = o00r[0], pk = packr[0];
        const _Float16* xc = xtb + (size_t)o00 * Cin + c4 * 8;   // cg=0
        int ob = (pk & 0xffff) << 6;                             // dx1 * 64
        int oc = (pk >> 16) << 13;                               // dyr * 8192
        ga = *(const half8*)(xc);
        gb = *(const half8*)(xc + ob);
        gc = *(const half8*)(xc + oc);
        gd = *(const half8*)(xc + oc + ob);
        ar0 = wsrc[(size_t)(2 * wv) * 64 + lane];
        ar1 = wsrc[(size_t)(2 * wv + 1) * 64 + lane];
    }
    __syncthreads();                       // P dead; p1 buffers live

#pragma unroll
    for (int ch = 0; ch < 18; ++ch) {
        int kt  = ch >> 1;
        int buf = ch & 1;
        // combine current chunk's gathers -> V f16
        union { unsigned u; _Float16 hh[2]; } u1, u2;
        u1.u = wab[kt];  u2.u = wcd[kt];
        float w00 = (float)u1.hh[0], w01 = (float)u1.hh[1];
        float w10 = (float)u2.hh[0], w11 = (float)u2.hh[1];
        half8 vv;
#pragma unroll
        for (int i = 0; i < 8; ++i) {
            float v = w00 * (float)ga[i] + w01 * (float)gb[i] +
                      w10 * (float)gc[i] + w11 * (float)gd[i];
            vv[i] = (_Float16)v;
        }
        *(half8*)&sm.p1.V[buf][q][c4 * 8] = vv;
        half8 a0c = ar0, a1c = ar1;
        // issue NEXT chunk's loads (stay in flight across the barrier)
        if (ch < 17) {
            int chn = ch + 1, ktn = chn >> 1, cgn = chn & 1;
            int o00 = o00r[ktn], pk = packr[ktn];
            const _Float16* xc = xtb + (size_t)o00 * Cin + cgn * 32 + c4 * 8;
            int ob = (pk & 0xffff) << 6;
            int oc = (pk >> 16) << 13;
            ga = *(const half8*)(xc);
            gb = *(const half8*)(xc + ob);
            gc = *(const half8*)(xc + oc);
            gd = *(const half8*)(xc + oc + ob);
            ar0 = wsrc[((size_t)chn * 8 + 2 * wv) * 64 + lane];
            ar1 = wsrc[((size_t)chn * 8 + 2 * wv + 1) * 64 + lane];
        }
        __syncthreads();
        // MFMA: 2 m-tiles x 4 n-tiles; A operands direct from registers
#pragma unroll
        for (int nt = 0; nt < 4; ++nt) {
            half8 bf = *(const half8*)&sm.p1.V[buf][nt * 16 + ln16][kq * 8];
            acc[0][nt] = __builtin_amdgcn_mfma_f32_16x16x32_f16(a0c, bf, acc[0][nt], 0, 0, 0);
            acc[1][nt] = __builtin_amdgcn_mfma_f32_16x16x32_f16(a1c, bf, acc[1][nt], 0, 0, 0);
        }
    }

    // epilogue: D col=lane&15 (pixel), row=(lane>>4)*4+reg (output)
#pragma unroll
    for (int mtl = 0; mtl < 2; ++mtl) {
#pragma unroll
        for (int nt = 0; nt < 4; ++nt) {
#pragma unroll
            for (int r = 0; r < 4; ++r) {
                int o  = m0 + mtl * 16 + kq * 4 + r;
                int px = nt * 16 + ln16;
                out[(size_t)(b * OUTC + o) * HW + pix0 + px] = acc[mtl][nt][r];
            }
        }
    }
}

// ---------------------------------------------------------------------------
extern "C" void kernel_launch(void* const* d_in, const int* in_sizes, int n_in,
                              void* d_out, int out_size, void* d_ws, size_t ws_size,
                              hipStream_t stream) {
    const float* x        = (const float*)d_in[0];
    const float* w_offset = (const float*)d_in[1];
    const float* b_offset = (const float*)d_in[2];
    const float* w_mask   = (const float*)d_in[3];
    const float* b_mask   = (const float*)d_in[4];
    const float* w_conv   = (const float*)d_in[5];
    float* out = (float*)d_out;

    _Float16* wpk_h = (_Float16*)d_ws;                   // 73,728 halves
    _Float16* wpk2  = wpk_h + 73728;                     // 18,432 halves
    _Float16* xtb   = wpk2 + 18432;                      // 8,388,608 halves (16.8 MB)

    transpose_x<<<1024, 256, 0, stream>>>(x, xtb);
    repack_w<<<288, 256, 0, stream>>>(w_conv, wpk_h);
    repack_w2<<<72, 256, 0, stream>>>(w_offset, w_mask, wpk2);
    deform_fused<<<2048, 256, 0, stream>>>(xtb, wpk_h, wpk2, b_offset, b_mask, out);
}